// Round 11
// baseline (2340.772 us; speedup 1.0000x reference)
//
#include <hip/hip_runtime.h>
#include <hip/hip_bf16.h>

// HMM backward recursion, B=32, T=256, H=1024, V=50257.
// y_s[b,i] = N_{s-1}[b] + log( sum_j expA[i,j] * Y_{s-1}[b,j] ) + e_t[b,i]
// Y_s = exp(y_s - N_s), N_s = max_i y_{s-1}[b,i] (one-step-stale upper bound).
// 16 persistent WGs, sc0sc1 data exchange (round-7 substrate).
// This round: (1) single-counter signaling (1 agent atomicAdd per wave per
// step; consumers poll ONE word, all lanes same address -> coalesced),
// (2) E-prefetch issued under the MFMA shadow with asm-pinned loads + vm8.

#define Hdim 1024
#define Bdim 32
#define Tdim 256
#define Vdim 50257
#define NWG  16
#define SLICE 64

typedef __attribute__((ext_vector_type(8))) __bf16 bf16x8;
typedef __attribute__((ext_vector_type(4))) float  f32x4;
typedef __attribute__((ext_vector_type(4))) unsigned u32x4;

// workspace layout (bytes)
#define OFF_ABF   0                          // exp(alpha) bf16: 2 MB
#define OFF_YBUF  2097152                    // [2][16][4096B] = 131072
#define OFF_PSUM  (OFF_YBUF + 131072)        // 32 f32 (pad 128)
#define OFF_RBUF  (OFF_PSUM + 128)           // 32 f32 (pad 128)
#define OFF_WREC  (OFF_RBUF + 128)           // [2][16][4] x 64B = 8192
#define OFF_CNT   (OFF_WREC + 8192)          // 2 counters, 128B stride
#define OFF_END0  (OFF_CNT + 256)
#define OFF_E     (((OFF_END0) + 4095) & ~4095)
#define WS_E_NEED ((size_t)OFF_E + (size_t)Tdim * Bdim * Hdim * 4)

// LDS carve
#define SM_A       131072                    // 64 rows x 1024 bf16 (swizzled)
#define SMEM_BYTES (SM_A + 256)

#define WAITCNT_VM(n) do { \
    asm volatile("s_waitcnt vmcnt(" #n ")" ::: "memory"); \
    __builtin_amdgcn_sched_barrier(0); } while (0)

// ---- sc0 sc1 (device-scope, cache-bypass) access helpers ----
__device__ __forceinline__ void st_b16_sc(void* p, unsigned v) {
    asm volatile("global_store_short %0, %1, off sc0 sc1" :: "v"(p), "v"(v) : "memory");
}
__device__ __forceinline__ void st_b128_sc(void* p, u32x4 v) {
    asm volatile("global_store_dwordx4 %0, %1, off sc0 sc1" :: "v"(p), "v"(v) : "memory");
}
__device__ __forceinline__ u32x4 ld_b128_sc(const void* p) {
    u32x4 r;
    asm volatile("global_load_dwordx4 %0, %1, off sc0 sc1" : "=v"(r) : "v"(p) : "memory");
    return r;
}
__device__ __forceinline__ float ld_f32_sc(const void* p) {
    float r;
    asm volatile("global_load_dword %0, %1, off sc0 sc1" : "=v"(r) : "v"(p) : "memory");
    return r;
}
__device__ __forceinline__ float ld_f32_cached(const void* p) {  // normal cached path
    float r;
    asm volatile("global_load_dword %0, %1, off" : "=v"(r) : "v"(p) : "memory");
    return r;
}

__global__ void k_expA(const float* __restrict__ alpha, __bf16* __restrict__ Abf) {
    int idx = (blockIdx.x * 256 + threadIdx.x) * 4;
    float4 v = *(const float4*)(alpha + idx);
    union { __bf16 h[4]; uint2 u; } cv;
    cv.h[0] = (__bf16)__expf(v.x);
    cv.h[1] = (__bf16)__expf(v.y);
    cv.h[2] = (__bf16)__expf(v.z);
    cv.h[3] = (__bf16)__expf(v.w);
    *(uint2*)(Abf + idx) = cv.u;
}

// E[t][b][i] = beta[i, x[b,t]]
__global__ void k_gather(const int* __restrict__ x, const float* __restrict__ beta,
                         float* __restrict__ E) {
    int tb = blockIdx.x;            // t*32 + b
    int t  = tb >> 5, b = tb & 31;
    int xv = x[b * Tdim + t];
    int i  = threadIdx.x * 4;
    float4 v;
    v.x = beta[(size_t)(i + 0) * Vdim + xv];
    v.y = beta[(size_t)(i + 1) * Vdim + xv];
    v.z = beta[(size_t)(i + 2) * Vdim + xv];
    v.w = beta[(size_t)(i + 3) * Vdim + xv];
    *(float4*)(E + ((size_t)t * Bdim + b) * Hdim + i) = v;
}

// compiler-load e (init + no-E fallback)
__device__ __forceinline__ void load_e(const float* __restrict__ E,
                                       const float* __restrict__ beta,
                                       const int* __restrict__ x,
                                       int t, int b0, int i0, int useE, float e[2][4]) {
    if (useE) {
        #pragma unroll
        for (int u = 0; u < 2; ++u)
            #pragma unroll
            for (int r = 0; r < 4; ++r)
                e[u][r] = E[((size_t)t * Bdim + (b0 + r)) * Hdim + i0 + u * 16];
    } else {
        int xv[4];
        #pragma unroll
        for (int r = 0; r < 4; ++r) xv[r] = x[(b0 + r) * Tdim + t];
        #pragma unroll
        for (int u = 0; u < 2; ++u)
            #pragma unroll
            for (int r = 0; r < 4; ++r)
                e[u][r] = beta[(size_t)(i0 + u * 16) * Vdim + xv[r]];
    }
}

// Per-WAVE publish (round-7 scatter form): Y direct from regs (16 b16 stores),
// per-b maxes as one b128 (li==0 lanes), own vm0 drain, then ONE counter add
// by lane 0. sched_barrier after vm0 pins later register copies (rule #18).
__device__ __forceinline__ void publish_wave(const float y[2][4], const float Gc[4],
                                             char* Yblk,     // Ybuf[par] + p*4096
                                             char* wrec_pw,  // wrec[par][p][w]
                                             unsigned* cnt_w,
                                             int l, int li, int g, int np, int b0) {
    float mx[4];
    #pragma unroll
    for (int r = 0; r < 4; ++r) {
        #pragma unroll
        for (int u = 0; u < 2; ++u) {
            float Yn = __expf(y[u][r] - Gc[r]);
            __bf16 h = (__bf16)Yn;
            unsigned hv = (unsigned)__builtin_bit_cast(unsigned short, h);
            st_b16_sc(Yblk + (b0 + r) * 128 + (np * 32 + u * 16 + li) * 2, hv);
        }
        float m = fmaxf(y[0][r], y[1][r]);
        m = fmaxf(m, __shfl_xor(m, 1, 16));
        m = fmaxf(m, __shfl_xor(m, 2, 16));
        m = fmaxf(m, __shfl_xor(m, 4, 16));
        m = fmaxf(m, __shfl_xor(m, 8, 16));
        mx[r] = m;
    }
    if (li == 0) {
        f32x4 mv = {mx[0], mx[1], mx[2], mx[3]};
        st_b128_sc(wrec_pw + g * 16, __builtin_bit_cast(u32x4, mv));
    }
    WAITCNT_VM(0);
    if (l == 0)
        __hip_atomic_fetch_add(cnt_w, 1u, __ATOMIC_RELAXED, __HIP_MEMORY_SCOPE_AGENT);
}

template<int USEE>
__launch_bounds__(256, 1)
__global__ void k_hmm(const int* __restrict__ x,
                      const float* __restrict__ beta,
                      const float* __restrict__ gamma,
                      const __bf16* __restrict__ Abf,
                      char* __restrict__ Yb,        // [2][16][4096B]
                      char* __restrict__ wrec,      // [2][16][4] x 64B
                      unsigned* __restrict__ cnt,   // [2] @ 128B stride
                      float* __restrict__ Psum,
                      float* __restrict__ Rbuf,
                      const float* __restrict__ Ebuf)
{
    extern __shared__ char smem[];
    char* Asl = smem;

    const int p   = blockIdx.x;
    const int tid = threadIdx.x;
    const int w   = tid >> 6;
    const int l   = tid & 63;
    const int g   = l >> 4;
    const int li  = l & 15;
    const int mb  = w & 1;
    const int np  = w >> 1;
    const int b0  = mb * 16 + g * 4;
    const int i0  = p * SLICE + np * 32 + li;

    // ---- stage A slice into LDS, XOR-swizzled for b128 reads ----
    #pragma unroll
    for (int rep = 0; rep < 32; ++rep) {
        int flat = rep * 256 + tid;
        int row  = flat >> 7;
        int c16  = flat & 127;
        uint4 v = *(const uint4*)((const char*)Abf + (size_t)(p * 64 + row) * 2048 + c16 * 16);
        int off = (row * 2048 + c16 * 16) ^ ((row & 7) << 4);
        *(uint4*)(Asl + off) = v;
    }
    __syncthreads();    // only barrier in the kernel (A staging)

    // gamma preload (compiler-managed waits; used only at the final step)
    const float gl0 = gamma[i0];
    const float gl1 = gamma[i0 + 16];

    // ---- init: y0 = e[:, T-1], publish per-wave to parity 0 ----
    {
        float y0[2][4];
        load_e(Ebuf, beta, x, Tdim - 1, b0, i0, USEE, y0);
        float Gc0[4] = {0.f, 0.f, 0.f, 0.f};
        publish_wave(y0, Gc0, Yb + p * 4096,
                     wrec + (size_t)p * 256 + w * 64,
                     cnt, l, li, g, np, b0);
    }

    float Nprev[4] = {0.f, 0.f, 0.f, 0.f};
    float ereg[2][4];
    float eregN[2][4];

    if constexpr (USEE) {
        const float* Et = Ebuf + (size_t)(Tdim - 2) * (Bdim * Hdim);
        #pragma unroll
        for (int u = 0; u < 2; ++u)
            #pragma unroll
            for (int r = 0; r < 4; ++r)
                ereg[u][r] = ld_f32_cached(Et + (b0 + r) * Hdim + i0 + u * 16);
        WAITCNT_VM(0);      // ereg landed; 0 outstanding at loop entry
    } else {
        load_e(Ebuf, beta, x, Tdim - 2, b0, i0, 0, ereg);
    }

    for (int s = 1; s < Tdim; ++s) {
        const int t     = Tdim - 1 - s;
        const int par_r = (s - 1) & 1;
        const int par_w = s & 1;

        if constexpr (!USEE) {
            if (s < Tdim - 1) load_e(Ebuf, beta, x, t - 1, b0, i0, 0, eregN);
            WAITCNT_VM(0);
        }

        // ---- poll ONE counter word (all lanes same address) ----
        {
            const unsigned tgt = 64u * (((unsigned)s + 1u) >> 1);
            unsigned* cp = cnt + (size_t)par_r * 32;   // 128B stride
            while (__hip_atomic_load(cp, __ATOMIC_RELAXED, __HIP_MEMORY_SCOPE_AGENT) < tgt) {}
        }

        // ---- issue Y loads (32 b128) ----
        const char* Ybase = Yb + (size_t)par_r * (NWG * 4096);
        const char* yrow  = Ybase + (mb * 16 + li) * 128 + g * 16;
        u32x4 yreg[32];
        #pragma unroll
        for (int kc = 0; kc < 32; ++kc)
            yreg[kc] = ld_b128_sc(yrow + (kc >> 1) * 4096 + (kc & 1) * 64);

        // ---- issue wrec loads (32 instrs, lanes<32) ----
        float gmv[32];
        {
            const char* wbase = wrec + (size_t)par_r * 4096;
            if (l < 32) {
                int bmb = l >> 4;
                int idx = (l & 15) * 4;
                #pragma unroll
                for (int q = 0; q < 16; ++q) {
                    gmv[2 * q]     = ld_f32_sc(wbase + q * 256 + bmb * 64 + idx);
                    gmv[2 * q + 1] = ld_f32_sc(wbase + q * 256 + (bmb + 2) * 64 + idx);
                }
            }
        }

        if constexpr (USEE) {
            // ---- issue next-step E loads (8, asm-pinned); land under MFMA ----
            const int tE = (t > 0) ? (t - 1) : 0;     // dummy at final step
            const float* Et = Ebuf + (size_t)tE * (Bdim * Hdim);
            #pragma unroll
            for (int u = 0; u < 2; ++u)
                #pragma unroll
                for (int r = 0; r < 4; ++r)
                    eregN[u][r] = ld_f32_cached(Et + (b0 + r) * Hdim + i0 + u * 16);
            WAITCNT_VM(8);    // 72 outstanding -> retires Y(32)+wrec(32); E flies
        } else {
            WAITCNT_VM(0);
        }

        // ---- S[b, i-slice] = sum_j expA[i,j] * Y[b,j] ----
        f32x4 acc0 = {0.f, 0.f, 0.f, 0.f}, acc1 = {0.f, 0.f, 0.f, 0.f};
        {
            const int ia = np * 32 + li;
            const int ib = ia + 16;
            const int basea = ia * 2048 + g * 16, xa = (ia & 7) << 4;
            const int baseb = ib * 2048 + g * 16, xb = (ib & 7) << 4;
            #pragma unroll
            for (int kc = 0; kc < 32; ++kc) {
                bf16x8 af0 = *(const bf16x8*)(Asl + ((basea + kc * 64) ^ xa));
                bf16x8 af1 = *(const bf16x8*)(Asl + ((baseb + kc * 64) ^ xb));
                bf16x8 yf  = __builtin_bit_cast(bf16x8, yreg[kc]);
                acc0 = __builtin_amdgcn_mfma_f32_16x16x32_bf16(yf, af0, acc0, 0, 0, 0);
                acc1 = __builtin_amdgcn_mfma_f32_16x16x32_bf16(yf, af1, acc1, 0, 0, 0);
            }
        }

        // per-b global max in registers + wave-local broadcast (wrec drained)
        float gm = -3.0e38f;
        if (l < 32) {
            #pragma unroll
            for (int q = 0; q < 32; ++q) gm = fmaxf(gm, gmv[q]);
        }
        float Gcur[4];
        #pragma unroll
        for (int r = 0; r < 4; ++r) Gcur[r] = __shfl(gm, b0 + r);

        float yv[2][4];
        #pragma unroll
        for (int r = 0; r < 4; ++r) {
            yv[0][r] = Nprev[r] + __logf(acc0[r]) + ereg[0][r];
            yv[1][r] = Nprev[r] + __logf(acc1[r]) + ereg[1][r];
        }

        if (s < Tdim - 1) {
            publish_wave(yv, Gcur,
                         Yb + (size_t)par_w * (NWG * 4096) + p * 4096,
                         wrec + (size_t)par_w * 4096 + (size_t)p * 256 + w * 64,
                         cnt + (size_t)par_w * 32,
                         l, li, g, np, b0);
            // publish's vm0+sched_barrier guarantees eregN landed before copies
            #pragma unroll
            for (int r = 0; r < 4; ++r) Nprev[r] = Gcur[r];
            #pragma unroll
            for (int u = 0; u < 2; ++u)
                #pragma unroll
                for (int r = 0; r < 4; ++r) ereg[u][r] = eregN[u][r];
        } else {
            #pragma unroll
            for (int r = 0; r < 4; ++r) {
                float pa = __expf(gl0 + yv[0][r] - Gcur[r])
                         + __expf(gl1 + yv[1][r] - Gcur[r]);
                pa += __shfl_xor(pa, 1, 16);
                pa += __shfl_xor(pa, 2, 16);
                pa += __shfl_xor(pa, 4, 16);
                pa += __shfl_xor(pa, 8, 16);
                if (li == 0) {
                    atomicAdd(&Psum[b0 + r], pa);
                    if (p == 0) Rbuf[b0 + r] = Gcur[r];
                }
            }
        }
    }
}

__global__ void k_final(const float* __restrict__ Psum, const float* __restrict__ Rbuf,
                        float* __restrict__ out) {
    int b = threadIdx.x;
    if (b < 32) out[b] = Rbuf[b] + __logf(Psum[b]);
}

extern "C" void kernel_launch(void* const* d_in, const int* in_sizes, int n_in,
                              void* d_out, int out_size, void* d_ws, size_t ws_size,
                              hipStream_t stream) {
    const int*   x     = (const int*)d_in[0];
    const float* alpha = (const float*)d_in[1];
    const float* beta  = (const float*)d_in[2];
    const float* gamma = (const float*)d_in[3];

    char* ws = (char*)d_ws;
    __bf16*   Abf  = (__bf16*)(ws + OFF_ABF);
    char*     Yb   = ws + OFF_YBUF;
    float*    Psum = (float*)(ws + OFF_PSUM);
    float*    Rbuf = (float*)(ws + OFF_RBUF);
    char*     wrec = ws + OFF_WREC;
    unsigned* cnt  = (unsigned*)(ws + OFF_CNT);
    float*    Ebuf = (float*)(ws + OFF_E);

    int useE = (ws_size >= WS_E_NEED) ? 1 : 0;

    // zero Psum/Rbuf/wrec/counters every launch
    (void)hipMemsetAsync(ws + OFF_PSUM, 0, OFF_END0 - OFF_PSUM, stream);

    hipLaunchKernelGGL(k_expA, dim3((Hdim * Hdim) / (256 * 4)), dim3(256), 0, stream, alpha, Abf);

    if (useE) {
        hipLaunchKernelGGL(k_gather, dim3(Tdim * Bdim), dim3(256), 0, stream, x, beta, Ebuf);
        (void)hipFuncSetAttribute((const void*)k_hmm<1>, hipFuncAttributeMaxDynamicSharedMemorySize, SMEM_BYTES);
        hipLaunchKernelGGL(k_hmm<1>, dim3(NWG), dim3(256), SMEM_BYTES, stream,
                           x, beta, gamma, Abf, Yb, wrec, cnt, Psum, Rbuf, Ebuf);
    } else {
        (void)hipFuncSetAttribute((const void*)k_hmm<0>, hipFuncAttributeMaxDynamicSharedMemorySize, SMEM_BYTES);
        hipLaunchKernelGGL(k_hmm<0>, dim3(NWG), dim3(256), SMEM_BYTES, stream,
                           x, beta, gamma, Abf, Yb, wrec, cnt, Psum, Rbuf, (const float*)nullptr);
    }

    hipLaunchKernelGGL(k_final, dim3(1), dim3(64), 0, stream, Psum, Rbuf, (float*)d_out);
}